// Round 1
// baseline (115.979 us; speedup 1.0000x reference)
//
#include <hip/hip_runtime.h>
#include <math.h>

#define NQ 10
#define NL 4
#define NSTATE 1024        // 2^NQ
#define NTHREADS 256

__global__ __launch_bounds__(NTHREADS) void qlayer_kernel(
    const float* __restrict__ x,    // (B, NQ)
    const float* __restrict__ qp,   // (NL*NQ*3,)
    float* __restrict__ out)        // (B, NQ)
{
    __shared__ float sRe[NSTATE];
    __shared__ float sIm[NSTATE];
    __shared__ float uRe[NL * NQ][4];
    __shared__ float uIm[NL * NQ][4];
    __shared__ float cosx[NQ], sinx[NQ];
    __shared__ float red[4][NQ];

    const int t = threadIdx.x;
    const int b = blockIdx.x;

    // --- build gate matrices U = Rz(w2) @ Ry(w1) @ Rx(w0), threads 0..39 ---
    if (t < NL * NQ) {
        float w0 = qp[t * 3 + 0], w1 = qp[t * 3 + 1], w2 = qp[t * 3 + 2];
        float cx = cosf(0.5f * w0), sx = sinf(0.5f * w0);
        float cy = cosf(0.5f * w1), sy = sinf(0.5f * w1);
        float er = cosf(0.5f * w2), ei = -sinf(0.5f * w2);  // ez = exp(-i*w2/2)
        // M = Ry @ Rx
        float m00r =  cy * cx, m00i =  sy * sx;
        float m01r = -sy * cx, m01i = -cy * sx;
        float m10r =  sy * cx, m10i = -cy * sx;
        float m11r =  cy * cx, m11i = -sy * sx;
        // U row0 = ez * M_row0 ; U row1 = conj(ez) * M_row1
        uRe[t][0] = er * m00r - ei * m00i;  uIm[t][0] = er * m00i + ei * m00r;
        uRe[t][1] = er * m01r - ei * m01i;  uIm[t][1] = er * m01i + ei * m01r;
        uRe[t][2] = er * m10r + ei * m10i;  uIm[t][2] = er * m10i - ei * m10r;
        uRe[t][3] = er * m11r + ei * m11i;  uIm[t][3] = er * m11i - ei * m11r;
    }
    if (t < NQ) {
        float h = 0.5f * x[b * NQ + t];
        cosx[t] = cosf(h);
        sinx[t] = sinf(h);
    }
    __syncthreads();

    // --- initial product state: amp(idx) = prod_i (bit_i ? sin : cos), bit_i = idx>>(9-i) ---
    #pragma unroll
    for (int k = 0; k < NSTATE / NTHREADS; ++k) {
        int idx = t + k * NTHREADS;
        float v = 1.0f;
        #pragma unroll
        for (int i = 0; i < NQ; ++i)
            v *= ((idx >> (NQ - 1 - i)) & 1) ? sinx[i] : cosx[i];
        sRe[idx] = v;
        sIm[idx] = 0.0f;
    }
    __syncthreads();

    // --- circuit ---
    for (int l = 0; l < NL; ++l) {
        // single-qubit gates
        for (int q = 0; q < NQ; ++q) {
            int g = l * NQ + q;
            float u0r = uRe[g][0], u0i = uIm[g][0];
            float u1r = uRe[g][1], u1i = uIm[g][1];
            float u2r = uRe[g][2], u2i = uIm[g][2];
            float u3r = uRe[g][3], u3i = uIm[g][3];
            int s = NQ - 1 - q;
            #pragma unroll
            for (int k = 0; k < 2; ++k) {
                int p = t + k * NTHREADS;          // pair index 0..511
                int low = p & ((1 << s) - 1);
                int idx0 = ((p >> s) << (s + 1)) | low;
                int idx1 = idx0 | (1 << s);
                float a0r = sRe[idx0], a0i = sIm[idx0];
                float a1r = sRe[idx1], a1i = sIm[idx1];
                sRe[idx0] = u0r * a0r - u0i * a0i + u1r * a1r - u1i * a1i;
                sIm[idx0] = u0r * a0i + u0i * a0r + u1r * a1i + u1i * a1r;
                sRe[idx1] = u2r * a0r - u2i * a0i + u3r * a1r - u3i * a1i;
                sIm[idx1] = u2r * a0i + u2i * a0r + u3r * a1i + u3i * a1r;
            }
            __syncthreads();
        }
        // CNOT chain: ctrl=q (shift st+1), tgt=q+1 (shift st)
        for (int q = 0; q < NQ - 1; ++q) {
            int st_ = NQ - 2 - q;
            int low = t & ((1 << st_) - 1);
            int idx0 = ((t >> st_) << (st_ + 2)) | (1 << (st_ + 1)) | low; // ctrl=1, tgt=0
            int idx1 = idx0 | (1 << st_);                                  // ctrl=1, tgt=1
            float r0 = sRe[idx0], i0 = sIm[idx0];
            float r1 = sRe[idx1], i1 = sIm[idx1];
            sRe[idx0] = r1; sIm[idx0] = i1;
            sRe[idx1] = r0; sIm[idx1] = i0;
            __syncthreads();
        }
    }

    // --- expectations <Z_i> = sum p(idx) * (1 - 2*bit_i) ---
    float ev[NQ];
    #pragma unroll
    for (int i = 0; i < NQ; ++i) ev[i] = 0.0f;
    #pragma unroll
    for (int k = 0; k < NSTATE / NTHREADS; ++k) {
        int idx = t + k * NTHREADS;
        float pr = sRe[idx] * sRe[idx] + sIm[idx] * sIm[idx];
        #pragma unroll
        for (int i = 0; i < NQ; ++i)
            ev[i] += ((idx >> (NQ - 1 - i)) & 1) ? -pr : pr;
    }
    #pragma unroll
    for (int i = 0; i < NQ; ++i) {
        #pragma unroll
        for (int off = 32; off >= 1; off >>= 1)
            ev[i] += __shfl_down(ev[i], off, 64);
    }
    int wave = t >> 6;
    int lane = t & 63;
    if (lane == 0) {
        #pragma unroll
        for (int i = 0; i < NQ; ++i) red[wave][i] = ev[i];
    }
    __syncthreads();
    if (t < NQ) {
        out[b * NQ + t] = red[0][t] + red[1][t] + red[2][t] + red[3][t];
    }
}

extern "C" void kernel_launch(void* const* d_in, const int* in_sizes, int n_in,
                              void* d_out, int out_size, void* d_ws, size_t ws_size,
                              hipStream_t stream) {
    const float* x  = (const float*)d_in[0];
    const float* qp = (const float*)d_in[1];
    float* out = (float*)d_out;
    const int B = in_sizes[0] / NQ;
    qlayer_kernel<<<B, NTHREADS, 0, stream>>>(x, qp, out);
}

// Round 2
// 100.298 us; speedup vs baseline: 1.1563x; 1.1563x over previous
//
#include <hip/hip_runtime.h>
#include <math.h>

#define NQ 10
#define NL 4
#define NGATES (NL * NQ)
#define NTHREADS 256
#define WAVES_PER_BLOCK 4

// Bit layout of the 1024-element state index, split across lane (6 bits) and
// per-lane registers (4 bits). Register qubits are the MIDDLE of the CNOT
// chain (qubits 3..6) so CNOTs 3,4,5 are free register renames:
//   qubit0 -> lane bit 5 (mask 32)   qubit3 -> reg bit 3 (8)
//   qubit1 -> lane bit 4 (16)        qubit4 -> reg bit 2 (4)
//   qubit2 -> lane bit 3 (8)         qubit5 -> reg bit 1 (2)
//   qubit7 -> lane bit 2 (4)         qubit6 -> reg bit 0 (1)
//   qubit8 -> lane bit 1 (2)
//   qubit9 -> lane bit 0 (1)

__global__ __launch_bounds__(NTHREADS) void qlayer_kernel(
    const float* __restrict__ x,    // (B, NQ)
    const float* __restrict__ qp,   // (NGATES*3,)
    float* __restrict__ out,        // (B, NQ)
    int B)
{
    __shared__ float4 su[NGATES][2];   // [g][0] = {u00r,u01r,u10r,u11r}, [g][1] = imag

    const int t = threadIdx.x;
    const int lane = t & 63;
    const int wave = t >> 6;
    const int b = blockIdx.x * WAVES_PER_BLOCK + wave;

    // --- build gate matrices U = Rz(w2) @ Ry(w1) @ Rx(w0), threads 0..39 ---
    if (t < NGATES) {
        float w0 = qp[t * 3 + 0], w1 = qp[t * 3 + 1], w2 = qp[t * 3 + 2];
        float cx = cosf(0.5f * w0), sx = sinf(0.5f * w0);
        float cy = cosf(0.5f * w1), sy = sinf(0.5f * w1);
        float er = cosf(0.5f * w2), ei = -sinf(0.5f * w2);  // ez = exp(-i*w2/2)
        // M = Ry @ Rx
        float m00r =  cy * cx, m00i =  sy * sx;
        float m01r = -sy * cx, m01i = -cy * sx;
        float m10r =  sy * cx, m10i = -cy * sx;
        float m11r =  cy * cx, m11i = -sy * sx;
        // U row0 = ez * M_row0 ; U row1 = conj(ez) * M_row1
        float4 r4, i4;
        r4.x = er * m00r - ei * m00i;  i4.x = er * m00i + ei * m00r;
        r4.y = er * m01r - ei * m01i;  i4.y = er * m01i + ei * m01r;
        r4.z = er * m10r + ei * m10i;  i4.z = er * m10i - ei * m10r;
        r4.w = er * m11r + ei * m11i;  i4.w = er * m11i - ei * m11r;
        su[t][0] = r4;
        su[t][1] = i4;
    }
    __syncthreads();
    if (b >= B) return;

    // --- per-qubit half-angle cos/sin (redundant per lane; SIMD-parallel) ---
    float c[NQ], s[NQ];
    #pragma unroll
    for (int q = 0; q < NQ; ++q) {
        float h = 0.5f * x[b * NQ + q];
        c[q] = cosf(h);
        s[q] = sinf(h);
    }

    // --- initial product state ---
    float lf = ((lane & 32) ? s[0] : c[0]) * ((lane & 16) ? s[1] : c[1]) *
               ((lane &  8) ? s[2] : c[2]) * ((lane &  4) ? s[7] : c[7]) *
               ((lane &  2) ? s[8] : c[8]) * ((lane &  1) ? s[9] : c[9]);
    float re[16], im[16];
    #pragma unroll
    for (int r = 0; r < 16; ++r) {
        re[r] = lf * ((r & 8) ? s[3] : c[3]) * ((r & 4) ? s[4] : c[4]) *
                     ((r & 2) ? s[5] : c[5]) * ((r & 1) ? s[6] : c[6]);
        im[r] = 0.0f;
    }

// --- gate macros (all strides/masks are compile-time constants) ---
#define LANE_GATE(G, M)                                                        \
    {                                                                          \
        float4 ur = su[G][0], ui = su[G][1];                                   \
        bool hi = (lane & (M)) != 0;                                           \
        float car = hi ? ur.w : ur.x, cai = hi ? ui.w : ui.x;                  \
        float cbr = hi ? ur.z : ur.y, cbi = hi ? ui.z : ui.y;                  \
        _Pragma("unroll")                                                      \
        for (int r = 0; r < 16; ++r) {                                         \
            float shr = __shfl_xor(re[r], (M), 64);                            \
            float shi = __shfl_xor(im[r], (M), 64);                            \
            float nr = car * re[r] - cai * im[r] + cbr * shr - cbi * shi;      \
            float ni = car * im[r] + cai * re[r] + cbr * shi + cbi * shr;      \
            re[r] = nr; im[r] = ni;                                            \
        }                                                                      \
    }

#define REG_GATE(G, S)                                                         \
    {                                                                          \
        float4 ur = su[G][0], ui = su[G][1];                                   \
        _Pragma("unroll")                                                      \
        for (int r0 = 0; r0 < 16; ++r0) if (!(r0 & (S))) {                     \
            int r1 = r0 | (S);                                                 \
            float a0r = re[r0], a0i = im[r0], a1r = re[r1], a1i = im[r1];      \
            re[r0] = ur.x * a0r - ui.x * a0i + ur.y * a1r - ui.y * a1i;        \
            im[r0] = ur.x * a0i + ui.x * a0r + ur.y * a1i + ui.y * a1r;        \
            re[r1] = ur.z * a0r - ui.z * a0i + ur.w * a1r - ui.w * a1i;        \
            im[r1] = ur.z * a0i + ui.z * a0r + ur.w * a1i + ui.w * a1r;        \
        }                                                                      \
    }

#define CNOT_LL(MC, MT)                                                        \
    {                                                                          \
        bool cc = (lane & (MC)) != 0;                                          \
        _Pragma("unroll")                                                      \
        for (int r = 0; r < 16; ++r) {                                         \
            float shr = __shfl_xor(re[r], (MT), 64);                           \
            float shi = __shfl_xor(im[r], (MT), 64);                           \
            re[r] = cc ? shr : re[r];                                          \
            im[r] = cc ? shi : im[r];                                          \
        }                                                                      \
    }

#define CNOT_LR(MC, S)                                                         \
    {                                                                          \
        bool cc = (lane & (MC)) != 0;                                          \
        _Pragma("unroll")                                                      \
        for (int r0 = 0; r0 < 16; ++r0) if (!(r0 & (S))) {                     \
            int r1 = r0 | (S);                                                 \
            float t0r = re[r0], t0i = im[r0];                                  \
            re[r0] = cc ? re[r1] : re[r0];  im[r0] = cc ? im[r1] : im[r0];     \
            re[r1] = cc ? t0r : re[r1];     im[r1] = cc ? t0i : im[r1];        \
        }                                                                      \
    }

#define CNOT_RR(SC, ST)                                                        \
    {                                                                          \
        _Pragma("unroll")                                                      \
        for (int r = 0; r < 16; ++r) if ((r & (SC)) && !(r & (ST))) {          \
            int r1 = r | (ST);                                                 \
            float tr = re[r], ti = im[r];                                      \
            re[r] = re[r1]; im[r] = im[r1];                                    \
            re[r1] = tr;    im[r1] = ti;                                       \
        }                                                                      \
    }

#define CNOT_RL(SC, MT)                                                        \
    {                                                                          \
        _Pragma("unroll")                                                      \
        for (int r = 0; r < 16; ++r) if (r & (SC)) {                           \
            re[r] = __shfl_xor(re[r], (MT), 64);                               \
            im[r] = __shfl_xor(im[r], (MT), 64);                               \
        }                                                                      \
    }

    // --- circuit: 4 layers, fully unrolled ---
    #pragma unroll
    for (int l = 0; l < NL; ++l) {
        int g = l * NQ;
        LANE_GATE(g + 0, 32)   // qubit 0
        LANE_GATE(g + 1, 16)   // qubit 1
        LANE_GATE(g + 2,  8)   // qubit 2
        REG_GATE (g + 3,  8)   // qubit 3
        REG_GATE (g + 4,  4)   // qubit 4
        REG_GATE (g + 5,  2)   // qubit 5
        REG_GATE (g + 6,  1)   // qubit 6
        LANE_GATE(g + 7,  4)   // qubit 7
        LANE_GATE(g + 8,  2)   // qubit 8
        LANE_GATE(g + 9,  1)   // qubit 9
        // CNOT chain (ctrl q, tgt q+1)
        CNOT_LL(32, 16)        // q=0: lane->lane
        CNOT_LL(16,  8)        // q=1
        CNOT_LR( 8,  8)        // q=2: lane ctrl -> reg tgt
        CNOT_RR( 8,  4)        // q=3: reg->reg (free)
        CNOT_RR( 4,  2)        // q=4
        CNOT_RR( 2,  1)        // q=5
        CNOT_RL( 1,  4)        // q=6: reg ctrl -> lane tgt
        CNOT_LL( 4,  2)        // q=7
        CNOT_LL( 2,  1)        // q=8
    }

    // --- expectations ---
    float p[16], P = 0.0f;
    #pragma unroll
    for (int r = 0; r < 16; ++r) {
        p[r] = re[r] * re[r] + im[r] * im[r];
        P += p[r];
    }
    float e3 = 0.0f, e4 = 0.0f, e5 = 0.0f, e6 = 0.0f;
    #pragma unroll
    for (int r = 0; r < 16; ++r) {
        e3 += (r & 8) ? -p[r] : p[r];
        e4 += (r & 4) ? -p[r] : p[r];
        e5 += (r & 2) ? -p[r] : p[r];
        e6 += (r & 1) ? -p[r] : p[r];
    }
    float ev[NQ];
    ev[0] = (lane & 32) ? -P : P;
    ev[1] = (lane & 16) ? -P : P;
    ev[2] = (lane &  8) ? -P : P;
    ev[3] = e3;
    ev[4] = e4;
    ev[5] = e5;
    ev[6] = e6;
    ev[7] = (lane &  4) ? -P : P;
    ev[8] = (lane &  2) ? -P : P;
    ev[9] = (lane &  1) ? -P : P;

    #pragma unroll
    for (int i = 0; i < NQ; ++i) {
        #pragma unroll
        for (int m = 32; m >= 1; m >>= 1)
            ev[i] += __shfl_xor(ev[i], m, 64);
    }
    if (lane == 0) {
        #pragma unroll
        for (int i = 0; i < NQ; ++i)
            out[b * NQ + i] = ev[i];
    }
}

extern "C" void kernel_launch(void* const* d_in, const int* in_sizes, int n_in,
                              void* d_out, int out_size, void* d_ws, size_t ws_size,
                              hipStream_t stream) {
    const float* x  = (const float*)d_in[0];
    const float* qp = (const float*)d_in[1];
    float* out = (float*)d_out;
    const int B = in_sizes[0] / NQ;
    const int blocks = (B + WAVES_PER_BLOCK - 1) / WAVES_PER_BLOCK;
    qlayer_kernel<<<blocks, NTHREADS, 0, stream>>>(x, qp, out, B);
}

// Round 3
// 87.895 us; speedup vs baseline: 1.3195x; 1.1411x over previous
//
#include <hip/hip_runtime.h>
#include <math.h>

#define NQ 10
#define NL 4
#define NGATES (NL * NQ)
#define NTHREADS 256
#define WPB 4   // waves per block

#if __has_builtin(__builtin_amdgcn_permlane32_swap)
#define HAVE_PLSWAP 1
#else
#define HAVE_PLSWAP 0
#endif

// ---------------------------------------------------------------------------
// Physical bit layout (10-bit state index split lane(6)/reg(4)):
//   qubit0 -> lane 16   qubit1 -> lane 8   qubit2 -> lane 4   (ds_swizzle bits)
//   qubit7 -> lane 32 (permlane)  qubit8 -> lane 2 (DPP)  qubit9 -> lane 1 (DPP)
//   qubit3 -> reg 8   qubit4 -> reg 4   qubit5 -> reg 2   qubit6 -> reg 1
// CNOT chain K = prefix-parity matrix; gates in layer l use
//   xor-mask m = K^{-l} e_q (Pascal), select s = row_q(K^l). All constexpr.
// ---------------------------------------------------------------------------

__global__ void prep_gates(const float* __restrict__ qp, float* __restrict__ ws) {
    int t = threadIdx.x;
    if (t >= NGATES) return;
    float w0 = qp[t * 3 + 0], w1 = qp[t * 3 + 1], w2 = qp[t * 3 + 2];
    float cx = cosf(0.5f * w0), sx = sinf(0.5f * w0);
    float cy = cosf(0.5f * w1), sy = sinf(0.5f * w1);
    float er = cosf(0.5f * w2), ei = -sinf(0.5f * w2);   // ez = exp(-i w2/2)
    // M = Ry @ Rx
    float m00r =  cy * cx, m00i =  sy * sx;
    float m01r = -sy * cx, m01i = -cy * sx;
    float m10r =  sy * cx, m10i = -cy * sx;
    float m11r =  cy * cx, m11i = -sy * sx;
    float4 r4, i4;
    r4.x = er * m00r - ei * m00i;  i4.x = er * m00i + ei * m00r;
    r4.y = er * m01r - ei * m01i;  i4.y = er * m01i + ei * m01r;
    r4.z = er * m10r + ei * m10i;  i4.z = er * m10i - ei * m10r;
    r4.w = er * m11r + ei * m11i;  i4.w = er * m11i - ei * m11r;
    float4* o = (float4*)(ws + t * 8);
    o[0] = r4;  o[1] = i4;
}

// generalized xor-exchange by compile-time lane mask XM
template<int XM>
__device__ __forceinline__ float exch(float v, int lane, bool selP) {
    if constexpr (XM == 0) return v;
    int x = __float_as_int(v);
    constexpr int low = XM & 31;
    if constexpr (low == 1)      x = __builtin_amdgcn_mov_dpp(x, 0xB1, 0xF, 0xF, true);
    else if constexpr (low == 2) x = __builtin_amdgcn_mov_dpp(x, 0x4E, 0xF, 0xF, true);
    else if constexpr (low == 3) x = __builtin_amdgcn_mov_dpp(x, 0x1B, 0xF, 0xF, true);
    else if constexpr (low != 0) x = __builtin_amdgcn_ds_swizzle(x, (low << 10) | 0x1F);
    if constexpr ((XM & 32) != 0) {
#if HAVE_PLSWAP
        auto r = __builtin_amdgcn_permlane32_swap((unsigned)x, (unsigned)x, false, false);
        x = selP ? (int)r[0] : (int)r[1];
#else
        x = __float_as_int(__shfl_xor(__int_as_float(x), 32, 64));
#endif
    }
    return __int_as_float(x);
}

// generalized 1q gate: pair (p, p^m); select h = parity(p & s)
template<int XM, int XR, int SL, int SR>
__device__ __forceinline__ void gate(float (&re)[16], float (&im)[16],
                                     float4 ur, float4 ui, int lane, bool selP) {
    bool hl = (__popc(lane & SL) & 1) != 0;
    // coeffs for reg-parity 0 (total h = hl) and reg-parity 1 (total h = !hl)
    float a0r = hl ? ur.w : ur.x, a0i = hl ? ui.w : ui.x;
    float b0r = hl ? ur.z : ur.y, b0i = hl ? ui.z : ui.y;
    float a1r = hl ? ur.x : ur.w, a1i = hl ? ui.x : ui.w;
    float b1r = hl ? ur.y : ur.z, b1i = hl ? ui.y : ui.z;
    float pre[16], pim[16];
    #pragma unroll
    for (int r = 0; r < 16; ++r) {
        pre[r] = exch<XM>(re[r ^ XR], lane, selP);
        pim[r] = exch<XM>(im[r ^ XR], lane, selP);
    }
    #pragma unroll
    for (int r = 0; r < 16; ++r) {
        const bool p1 = (__builtin_popcount(r & SR) & 1) != 0;  // compile-time
        float ar = p1 ? a1r : a0r, ai = p1 ? a1i : a0i;
        float br = p1 ? b1r : b0r, bi = p1 ? b1i : b0i;
        float nr = ar * re[r] - ai * im[r] + br * pre[r] - bi * pim[r];
        float ni = ar * im[r] + ai * re[r] + br * pim[r] + bi * pre[r];
        re[r] = nr;  im[r] = ni;
    }
}

// 6-stage signed butterfly: lane L ends with sum_j (-1)^{popcount(L&j)} v_j
__device__ __forceinline__ float wht6(float v, int lane, bool selP) {
    float t;
    t = exch<1>(v, lane, selP);   v = (lane & 1)  ? (t - v) : (v + t);
    t = exch<2>(v, lane, selP);   v = (lane & 2)  ? (t - v) : (v + t);
    t = exch<4>(v, lane, selP);   v = (lane & 4)  ? (t - v) : (v + t);
    t = exch<8>(v, lane, selP);   v = (lane & 8)  ? (t - v) : (v + t);
    t = exch<16>(v, lane, selP);  v = (lane & 16) ? (t - v) : (v + t);
    t = exch<32>(v, lane, selP);  v = (lane & 32) ? (t - v) : (v + t);
    return v;
}

__global__ __launch_bounds__(NTHREADS) void qlayer_kernel(
    const float* __restrict__ x,
    const float* __restrict__ gw,   // 40 gates x 8 floats (from prep)
    float* __restrict__ out,
    int B)
{
    const int lane = threadIdx.x & 63;
    const int b = blockIdx.x * WPB + (threadIdx.x >> 6);
    if (b >= B) return;

    // runtime probe: which permlane32_swap output holds the lane^32 partner
    bool selP = false;
#if HAVE_PLSWAP
    {
        auto pr = __builtin_amdgcn_permlane32_swap((unsigned)lane, (unsigned)lane, false, false);
        selP = ((int)pr[0] == (lane ^ 32));
    }
#endif

    float c[NQ], s[NQ];
    #pragma unroll
    for (int q = 0; q < NQ; ++q) {
        float h = 0.5f * x[b * NQ + q];
        c[q] = cosf(h);  s[q] = sinf(h);
    }

    // initial product state per physical layout
    float lf = ((lane & 16) ? s[0] : c[0]) * ((lane & 8) ? s[1] : c[1]) *
               ((lane &  4) ? s[2] : c[2]) * ((lane & 32) ? s[7] : c[7]) *
               ((lane &  2) ? s[8] : c[8]) * ((lane &  1) ? s[9] : c[9]);
    float re[16], im[16];
    #pragma unroll
    for (int r = 0; r < 16; ++r) {
        re[r] = lf * ((r & 8) ? s[3] : c[3]) * ((r & 4) ? s[4] : c[4]) *
                     ((r & 2) ? s[5] : c[5]) * ((r & 1) ? s[6] : c[6]);
        im[r] = 0.0f;
    }

    const float4* gm = (const float4*)gw;
#define GATE(L, Q, XM, XR, SLm, SRm) \
    gate<XM, XR, SLm, SRm>(re, im, gm[((L)*NQ+(Q))*2], gm[((L)*NQ+(Q))*2+1], lane, selP);

    // layer 0 (A = I)
    GATE(0,0, 16,0, 16,0)  GATE(0,1, 8,0, 8,0)   GATE(0,2, 4,0, 4,0)
    GATE(0,3, 0,8, 0,8)    GATE(0,4, 0,4, 0,4)   GATE(0,5, 0,2, 0,2)
    GATE(0,6, 0,1, 0,1)    GATE(0,7, 32,0, 32,0) GATE(0,8, 2,0, 2,0)
    GATE(0,9, 1,0, 1,0)
    // layer 1 (A = K): m={q,q+1}, s={0..q}
    GATE(1,0, 24,0, 16,0)  GATE(1,1, 12,0, 24,0) GATE(1,2, 4,8, 28,0)
    GATE(1,3, 0,12, 28,8)  GATE(1,4, 0,6, 28,12) GATE(1,5, 0,3, 28,14)
    GATE(1,6, 32,1, 28,15) GATE(1,7, 34,0, 60,15) GATE(1,8, 3,0, 62,15)
    GATE(1,9, 1,0, 63,15)
    // layer 2 (A = K^2): m={q,q+2}, s={q,q-2,...}
    GATE(2,0, 20,0, 16,0)  GATE(2,1, 8,8, 8,0)   GATE(2,2, 4,4, 20,0)
    GATE(2,3, 0,10, 8,8)   GATE(2,4, 0,5, 20,4)  GATE(2,5, 32,2, 8,10)
    GATE(2,6, 2,1, 20,5)   GATE(2,7, 33,0, 40,10) GATE(2,8, 2,0, 22,5)
    GATE(2,9, 1,0, 41,10)
    // layer 3 (A = K^3): m={q..q+3}, s={q,q-1,q-4,q-5,q-8,q-9}
    GATE(3,0, 28,8, 16,0)  GATE(3,1, 12,12, 24,0) GATE(3,2, 4,14, 12,0)
    GATE(3,3, 0,15, 4,8)   GATE(3,4, 32,7, 16,12) GATE(3,5, 34,3, 24,6)
    GATE(3,6, 35,1, 12,3)  GATE(3,7, 35,0, 36,9)  GATE(3,8, 3,0, 50,12)
    GATE(3,9, 1,0, 27,6)
#undef GATE

    // epilogue: probabilities, reg-space signed folds, 5 lane-space WHTs
    float p[16];
    #pragma unroll
    for (int r = 0; r < 16; ++r) p[r] = re[r] * re[r] + im[r] * im[r];
    float a[8], f8 = 0.0f;
    #pragma unroll
    for (int r = 0; r < 8; ++r) { a[r] = p[r] + p[r + 8]; f8 += p[r] - p[r + 8]; }
    float c4[4], f4 = 0.0f;
    #pragma unroll
    for (int r = 0; r < 4; ++r) { c4[r] = a[r] + a[r + 4]; f4 += a[r] - a[r + 4]; }
    float e2[2], f2 = 0.0f;
    #pragma unroll
    for (int r = 0; r < 2; ++r) { e2[r] = c4[r] + c4[r + 2]; f2 += c4[r] - c4[r + 2]; }
    float P  = e2[0] + e2[1];
    float f1 = e2[0] - e2[1];

    float wP = wht6(P,  lane, selP);
    float w8 = wht6(f8, lane, selP);
    float w4 = wht6(f4, lane, selP);
    float w2 = wht6(f2, lane, selP);
    float w1 = wht6(f1, lane, selP);

    // rows of K^4: {i, i-4, i-8} -> (value, lane index)
    float* o = out + b * NQ;
    if (lane == 16) { o[0] = wP; o[4] = w4; }
    if (lane ==  8) { o[1] = wP; o[5] = w2; }
    if (lane ==  4) { o[2] = wP; o[6] = w1; }
    if (lane ==  0) { o[3] = w8; }
    if (lane == 32) { o[7] = w8; }
    if (lane == 18) { o[8] = w4; }
    if (lane ==  9) { o[9] = w2; }
}

extern "C" void kernel_launch(void* const* d_in, const int* in_sizes, int n_in,
                              void* d_out, int out_size, void* d_ws, size_t ws_size,
                              hipStream_t stream) {
    const float* x  = (const float*)d_in[0];
    const float* qp = (const float*)d_in[1];
    float* out = (float*)d_out;
    float* ws  = (float*)d_ws;
    const int B = in_sizes[0] / NQ;
    prep_gates<<<1, 64, 0, stream>>>(qp, ws);
    const int blocks = (B + WPB - 1) / WPB;
    qlayer_kernel<<<blocks, NTHREADS, 0, stream>>>(x, ws, out, B);
}

// Round 4
// 84.807 us; speedup vs baseline: 1.3676x; 1.0364x over previous
//
#include <hip/hip_runtime.h>
#include <math.h>

#define NQ 10
#define NL 4
#define NGATES (NL * NQ)
#define NTHREADS 256
#define WPB 4   // waves per block

#if __has_builtin(__builtin_amdgcn_permlane32_swap)
#define HAVE_PLSWAP 1
#else
#define HAVE_PLSWAP 0
#endif

// ---------------------------------------------------------------------------
// Physical bit layout (10-bit state index split lane(6)/reg(4)):
//   qubit0 -> lane 16   qubit1 -> lane 8   qubit2 -> lane 4   (ds_swizzle bits)
//   qubit7 -> lane 32 (permlane)  qubit8 -> lane 2 (DPP)  qubit9 -> lane 1 (DPP)
//   qubit3 -> reg 8   qubit4 -> reg 4   qubit5 -> reg 2   qubit6 -> reg 1
// CNOT chain K = prefix-parity matrix; CNOTs are absorbed into basis
// relabeling. Gate on qubit q in layer l uses xor-mask m = K^{-l} e_q and
// select-parity s = row_q(K^l); all 40 (mask, select) pairs are constexpr
// (verified vs reference in rounds 2-3).
// ---------------------------------------------------------------------------

// generalized xor-exchange by compile-time lane mask XM
template<int XM>
__device__ __forceinline__ float exch(float v, int lane, bool selP) {
    if constexpr (XM == 0) return v;
    int x = __float_as_int(v);
    constexpr int low = XM & 31;
    if constexpr (low == 1)      x = __builtin_amdgcn_mov_dpp(x, 0xB1, 0xF, 0xF, true);
    else if constexpr (low == 2) x = __builtin_amdgcn_mov_dpp(x, 0x4E, 0xF, 0xF, true);
    else if constexpr (low == 3) x = __builtin_amdgcn_mov_dpp(x, 0x1B, 0xF, 0xF, true);
    else if constexpr (low != 0) x = __builtin_amdgcn_ds_swizzle(x, (low << 10) | 0x1F);
    if constexpr ((XM & 32) != 0) {
#if HAVE_PLSWAP
        auto r = __builtin_amdgcn_permlane32_swap((unsigned)x, (unsigned)x, false, false);
        x = selP ? (int)r[0] : (int)r[1];
#else
        x = __float_as_int(__shfl_xor(__int_as_float(x), 32, 64));
#endif
    }
    return __int_as_float(x);
}

// generalized 1q gate: pair (p, p^m); select h = parity(p & s)
template<int XM, int XR, int SL, int SR>
__device__ __forceinline__ void gate(float (&re)[16], float (&im)[16],
                                     float4 ur, float4 ui, int lane, bool selP) {
    bool hl = (__popc(lane & SL) & 1) != 0;
    float a0r = hl ? ur.w : ur.x, a0i = hl ? ui.w : ui.x;
    float b0r = hl ? ur.z : ur.y, b0i = hl ? ui.z : ui.y;
    float a1r = hl ? ur.x : ur.w, a1i = hl ? ui.x : ui.w;
    float b1r = hl ? ur.y : ur.z, b1i = hl ? ui.y : ui.z;
    float pre[16], pim[16];
    #pragma unroll
    for (int r = 0; r < 16; ++r) {
        pre[r] = exch<XM>(re[r ^ XR], lane, selP);
        pim[r] = exch<XM>(im[r ^ XR], lane, selP);
    }
    #pragma unroll
    for (int r = 0; r < 16; ++r) {
        const bool p1 = (__builtin_popcount(r & SR) & 1) != 0;  // compile-time
        float ar = p1 ? a1r : a0r, ai = p1 ? a1i : a0i;
        float br = p1 ? b1r : b0r, bi = p1 ? b1i : b0i;
        float nr = ar * re[r] - ai * im[r] + br * pre[r] - bi * pim[r];
        float ni = ar * im[r] + ai * re[r] + br * pim[r] + bi * pre[r];
        re[r] = nr;  im[r] = ni;
    }
}

// 6-stage signed butterfly: lane L ends with sum_j (-1)^{popcount(L&j)} v_j
__device__ __forceinline__ float wht6(float v, int lane, bool selP) {
    float t;
    t = exch<1>(v, lane, selP);   v = (lane & 1)  ? (t - v) : (v + t);
    t = exch<2>(v, lane, selP);   v = (lane & 2)  ? (t - v) : (v + t);
    t = exch<4>(v, lane, selP);   v = (lane & 4)  ? (t - v) : (v + t);
    t = exch<8>(v, lane, selP);   v = (lane & 8)  ? (t - v) : (v + t);
    t = exch<16>(v, lane, selP);  v = (lane & 16) ? (t - v) : (v + t);
    t = exch<32>(v, lane, selP);  v = (lane & 32) ? (t - v) : (v + t);
    return v;
}

__global__ __launch_bounds__(NTHREADS) void qlayer_kernel(
    const float* __restrict__ x,
    const float* __restrict__ qp,
    float* __restrict__ out,
    int B)
{
    __shared__ float4 su[NGATES][2];   // [g][0]={u00r,u01r,u10r,u11r}, [g][1]=imag

    const int t = threadIdx.x;
    // --- build gate matrices U = Rz @ Ry @ Rx, threads 0..39 ---
    if (t < NGATES) {
        float w0 = qp[t * 3 + 0], w1 = qp[t * 3 + 1], w2 = qp[t * 3 + 2];
        float cx = cosf(0.5f * w0), sx = sinf(0.5f * w0);
        float cy = cosf(0.5f * w1), sy = sinf(0.5f * w1);
        float er = cosf(0.5f * w2), ei = -sinf(0.5f * w2);   // ez = exp(-i w2/2)
        float m00r =  cy * cx, m00i =  sy * sx;
        float m01r = -sy * cx, m01i = -cy * sx;
        float m10r =  sy * cx, m10i = -cy * sx;
        float m11r =  cy * cx, m11i = -sy * sx;
        float4 r4, i4;
        r4.x = er * m00r - ei * m00i;  i4.x = er * m00i + ei * m00r;
        r4.y = er * m01r - ei * m01i;  i4.y = er * m01i + ei * m01r;
        r4.z = er * m10r + ei * m10i;  i4.z = er * m10i - ei * m10r;
        r4.w = er * m11r + ei * m11i;  i4.w = er * m11i - ei * m11r;
        su[t][0] = r4;  su[t][1] = i4;
    }
    __syncthreads();

    const int lane = t & 63;
    const int b = blockIdx.x * WPB + (t >> 6);
    if (b >= B) return;

    // runtime probe: which permlane32_swap output holds the lane^32 partner
    bool selP = false;
#if HAVE_PLSWAP
    {
        auto pr = __builtin_amdgcn_permlane32_swap((unsigned)lane, (unsigned)lane, false, false);
        selP = ((int)pr[0] == (lane ^ 32));
    }
#endif

    float c[NQ], s[NQ];
    #pragma unroll
    for (int q = 0; q < NQ; ++q) {
        float h = 0.5f * x[b * NQ + q];
        c[q] = cosf(h);  s[q] = sinf(h);
    }

    // initial product state per physical layout
    float lf = ((lane & 16) ? s[0] : c[0]) * ((lane & 8) ? s[1] : c[1]) *
               ((lane &  4) ? s[2] : c[2]) * ((lane & 32) ? s[7] : c[7]) *
               ((lane &  2) ? s[8] : c[8]) * ((lane &  1) ? s[9] : c[9]);
    float re[16], im[16];
    #pragma unroll
    for (int r = 0; r < 16; ++r) {
        re[r] = lf * ((r & 8) ? s[3] : c[3]) * ((r & 4) ? s[4] : c[4]) *
                     ((r & 2) ? s[5] : c[5]) * ((r & 1) ? s[6] : c[6]);
        im[r] = 0.0f;
    }

#define GATE(L, Q, XM, XR, SLm, SRm) \
    gate<XM, XR, SLm, SRm>(re, im, su[(L)*NQ+(Q)][0], su[(L)*NQ+(Q)][1], lane, selP);

    // layer 0 (A = I)
    GATE(0,0, 16,0, 16,0)  GATE(0,1, 8,0, 8,0)   GATE(0,2, 4,0, 4,0)
    GATE(0,3, 0,8, 0,8)    GATE(0,4, 0,4, 0,4)   GATE(0,5, 0,2, 0,2)
    GATE(0,6, 0,1, 0,1)    GATE(0,7, 32,0, 32,0) GATE(0,8, 2,0, 2,0)
    GATE(0,9, 1,0, 1,0)
    // layer 1 (A = K)
    GATE(1,0, 24,0, 16,0)  GATE(1,1, 12,0, 24,0) GATE(1,2, 4,8, 28,0)
    GATE(1,3, 0,12, 28,8)  GATE(1,4, 0,6, 28,12) GATE(1,5, 0,3, 28,14)
    GATE(1,6, 32,1, 28,15) GATE(1,7, 34,0, 60,15) GATE(1,8, 3,0, 62,15)
    GATE(1,9, 1,0, 63,15)
    // layer 2 (A = K^2)
    GATE(2,0, 20,0, 16,0)  GATE(2,1, 8,8, 8,0)   GATE(2,2, 4,4, 20,0)
    GATE(2,3, 0,10, 8,8)   GATE(2,4, 0,5, 20,4)  GATE(2,5, 32,2, 8,10)
    GATE(2,6, 2,1, 20,5)   GATE(2,7, 33,0, 40,10) GATE(2,8, 2,0, 22,5)
    GATE(2,9, 1,0, 41,10)
    // layer 3 (A = K^3)
    GATE(3,0, 28,8, 16,0)  GATE(3,1, 12,12, 24,0) GATE(3,2, 4,14, 12,0)
    GATE(3,3, 0,15, 4,8)   GATE(3,4, 32,7, 16,12) GATE(3,5, 34,3, 24,6)
    GATE(3,6, 35,1, 12,3)  GATE(3,7, 35,0, 36,9)  GATE(3,8, 3,0, 50,12)
    GATE(3,9, 1,0, 27,6)
#undef GATE

    // epilogue: probabilities, reg-space signed folds, 5 lane-space WHTs
    float p[16];
    #pragma unroll
    for (int r = 0; r < 16; ++r) p[r] = re[r] * re[r] + im[r] * im[r];
    float a[8], f8 = 0.0f;
    #pragma unroll
    for (int r = 0; r < 8; ++r) { a[r] = p[r] + p[r + 8]; f8 += p[r] - p[r + 8]; }
    float c4[4], f4 = 0.0f;
    #pragma unroll
    for (int r = 0; r < 4; ++r) { c4[r] = a[r] + a[r + 4]; f4 += a[r] - a[r + 4]; }
    float e2[2], f2 = 0.0f;
    #pragma unroll
    for (int r = 0; r < 2; ++r) { e2[r] = c4[r] + c4[r + 2]; f2 += c4[r] - c4[r + 2]; }
    float P  = e2[0] + e2[1];
    float f1 = e2[0] - e2[1];

    float wP = wht6(P,  lane, selP);
    float w8 = wht6(f8, lane, selP);
    float w4 = wht6(f4, lane, selP);
    float w2 = wht6(f2, lane, selP);
    float w1 = wht6(f1, lane, selP);

    // rows of K^4: {i, i-4, i-8} -> (value, lane index)
    float* o = out + b * NQ;
    if (lane == 16) { o[0] = wP; o[4] = w4; }
    if (lane ==  8) { o[1] = wP; o[5] = w2; }
    if (lane ==  4) { o[2] = wP; o[6] = w1; }
    if (lane ==  0) { o[3] = w8; }
    if (lane == 32) { o[7] = w8; }
    if (lane == 18) { o[8] = w4; }
    if (lane ==  9) { o[9] = w2; }
}

extern "C" void kernel_launch(void* const* d_in, const int* in_sizes, int n_in,
                              void* d_out, int out_size, void* d_ws, size_t ws_size,
                              hipStream_t stream) {
    const float* x  = (const float*)d_in[0];
    const float* qp = (const float*)d_in[1];
    float* out = (float*)d_out;
    const int B = in_sizes[0] / NQ;
    const int blocks = (B + WPB - 1) / WPB;
    qlayer_kernel<<<blocks, NTHREADS, 0, stream>>>(x, qp, out, B);
}

// Round 5
// 80.276 us; speedup vs baseline: 1.4448x; 1.0564x over previous
//
#include <hip/hip_runtime.h>
#include <math.h>

#define NQ 10
#define NL 4
#define NGATES (NL * NQ)
#define NTHREADS 256
#define WPB 4   // waves per block

#if __has_builtin(__builtin_amdgcn_permlane32_swap)
#define HAVE_PLSWAP 1
#else
#define HAVE_PLSWAP 0
#endif

// ---------------------------------------------------------------------------
// Physical bit layout (10-bit state index split lane(6)/reg(4)):
//   qubit0 -> lane 16   qubit1 -> lane 8   qubit2 -> lane 4   (ds_swizzle bits)
//   qubit7 -> lane 32 (permlane)  qubit8 -> lane 2 (DPP)  qubit9 -> lane 1 (DPP)
//   qubit3 -> reg 8   qubit4 -> reg 4   qubit5 -> reg 2   qubit6 -> reg 1
// CNOT chain K = prefix-parity matrix; CNOTs absorbed into basis relabeling.
// Gate on qubit q in layer l: xor-mask m = K^{-l} e_q, select s = row_q(K^l).
// All 40 (mask, select) pairs constexpr (validated rounds 2-4).
// ---------------------------------------------------------------------------

// generalized xor-exchange by compile-time lane mask XM
template<int XM>
__device__ __forceinline__ float exch(float v, int lane, bool selP) {
    if constexpr (XM == 0) return v;
    int x = __float_as_int(v);
    constexpr int low = XM & 31;
    if constexpr (low == 1)      x = __builtin_amdgcn_mov_dpp(x, 0xB1, 0xF, 0xF, true);
    else if constexpr (low == 2) x = __builtin_amdgcn_mov_dpp(x, 0x4E, 0xF, 0xF, true);
    else if constexpr (low == 3) x = __builtin_amdgcn_mov_dpp(x, 0x1B, 0xF, 0xF, true);
    else if constexpr (low != 0) x = __builtin_amdgcn_ds_swizzle(x, (low << 10) | 0x1F);
    if constexpr ((XM & 32) != 0) {
#if HAVE_PLSWAP
        auto r = __builtin_amdgcn_permlane32_swap((unsigned)x, (unsigned)x, false, false);
        x = selP ? (int)r[0] : (int)r[1];
#else
        x = __float_as_int(__shfl_xor(__int_as_float(x), 32, 64));
#endif
    }
    return __int_as_float(x);
}

// generalized 1q gate: pair (p, p^m); select h = parity(p & s)
template<int XM, int XR, int SL, int SR>
__device__ __forceinline__ void gate(float (&re)[16], float (&im)[16],
                                     float4 ur, float4 ui, int lane, bool selP) {
    bool hl = (__popc(lane & SL) & 1) != 0;
    float a0r = hl ? ur.w : ur.x, a0i = hl ? ui.w : ui.x;
    float b0r = hl ? ur.z : ur.y, b0i = hl ? ui.z : ui.y;
    float a1r = hl ? ur.x : ur.w, a1i = hl ? ui.x : ui.w;
    float b1r = hl ? ur.y : ur.z, b1i = hl ? ui.y : ui.z;
    float pre[16], pim[16];
    #pragma unroll
    for (int r = 0; r < 16; ++r) {
        pre[r] = exch<XM>(re[r ^ XR], lane, selP);
        pim[r] = exch<XM>(im[r ^ XR], lane, selP);
    }
    #pragma unroll
    for (int r = 0; r < 16; ++r) {
        const bool p1 = (__builtin_popcount(r & SR) & 1) != 0;  // compile-time
        float ar = p1 ? a1r : a0r, ai = p1 ? a1i : a0i;
        float br = p1 ? b1r : b0r, bi = p1 ? b1i : b0i;
        float nr = ar * re[r] - ai * im[r] + br * pre[r] - bi * pim[r];
        float ni = ar * im[r] + ai * re[r] + br * pim[r] + bi * pre[r];
        re[r] = nr;  im[r] = ni;
    }
}

// 6-stage signed butterfly: lane L ends with sum_j (-1)^{popcount(L&j)} v_j
__device__ __forceinline__ float wht6(float v, int lane, bool selP) {
    float t;
    t = exch<1>(v, lane, selP);   v = (lane & 1)  ? (t - v) : (v + t);
    t = exch<2>(v, lane, selP);   v = (lane & 2)  ? (t - v) : (v + t);
    t = exch<4>(v, lane, selP);   v = (lane & 4)  ? (t - v) : (v + t);
    t = exch<8>(v, lane, selP);   v = (lane & 8)  ? (t - v) : (v + t);
    t = exch<16>(v, lane, selP);  v = (lane & 16) ? (t - v) : (v + t);
    t = exch<32>(v, lane, selP);  v = (lane & 32) ? (t - v) : (v + t);
    return v;
}

__global__ __launch_bounds__(NTHREADS, 2) void qlayer_kernel(
    const float* __restrict__ x,
    const float* __restrict__ qp,
    float* __restrict__ out,
    int B)
{
    __shared__ float4 su[NGATES][2];   // [g][0]={u00r,u01r,u10r,u11r}, [g][1]=imag

    const int t = threadIdx.x;
    // --- build gate matrices U = Rz @ Ry @ Rx, threads 0..39 ---
    if (t < NGATES) {
        float w0 = qp[t * 3 + 0], w1 = qp[t * 3 + 1], w2 = qp[t * 3 + 2];
        float cx = __cosf(0.5f * w0), sx = __sinf(0.5f * w0);
        float cy = __cosf(0.5f * w1), sy = __sinf(0.5f * w1);
        float er = __cosf(0.5f * w2), ei = -__sinf(0.5f * w2);   // ez = exp(-i w2/2)
        float m00r =  cy * cx, m00i =  sy * sx;
        float m01r = -sy * cx, m01i = -cy * sx;
        float m10r =  sy * cx, m10i = -cy * sx;
        float m11r =  cy * cx, m11i = -sy * sx;
        float4 r4, i4;
        r4.x = er * m00r - ei * m00i;  i4.x = er * m00i + ei * m00r;
        r4.y = er * m01r - ei * m01i;  i4.y = er * m01i + ei * m01r;
        r4.z = er * m10r + ei * m10i;  i4.z = er * m10i - ei * m10r;
        r4.w = er * m11r + ei * m11i;  i4.w = er * m11i - ei * m11r;
        su[t][0] = r4;  su[t][1] = i4;
    }
    __syncthreads();

    const int lane = t & 63;
    const int b = blockIdx.x * WPB + (t >> 6);
    if (b >= B) return;

    // runtime probe: which permlane32_swap output holds the lane^32 partner
    bool selP = false;
#if HAVE_PLSWAP
    {
        auto pr = __builtin_amdgcn_permlane32_swap((unsigned)lane, (unsigned)lane, false, false);
        selP = ((int)pr[0] == (lane ^ 32));
    }
#endif

    float c[NQ], s[NQ];
    #pragma unroll
    for (int q = 0; q < NQ; ++q) {
        float h = 0.5f * x[b * NQ + q];
        c[q] = __cosf(h);  s[q] = __sinf(h);
    }

    // initial product state per physical layout
    float lf = ((lane & 16) ? s[0] : c[0]) * ((lane & 8) ? s[1] : c[1]) *
               ((lane &  4) ? s[2] : c[2]) * ((lane & 32) ? s[7] : c[7]) *
               ((lane &  2) ? s[8] : c[8]) * ((lane &  1) ? s[9] : c[9]);
    float re[16], im[16];
    #pragma unroll
    for (int r = 0; r < 16; ++r) {
        re[r] = lf * ((r & 8) ? s[3] : c[3]) * ((r & 4) ? s[4] : c[4]) *
                     ((r & 2) ? s[5] : c[5]) * ((r & 1) ? s[6] : c[6]);
        im[r] = 0.0f;
    }

#define GATE(L, Q, XM, XR, SLm, SRm) \
    gate<XM, XR, SLm, SRm>(re, im, su[(L)*NQ+(Q)][0], su[(L)*NQ+(Q)][1], lane, selP);

    // layer 0 (A = I)
    GATE(0,0, 16,0, 16,0)  GATE(0,1, 8,0, 8,0)   GATE(0,2, 4,0, 4,0)
    GATE(0,3, 0,8, 0,8)    GATE(0,4, 0,4, 0,4)   GATE(0,5, 0,2, 0,2)
    GATE(0,6, 0,1, 0,1)    GATE(0,7, 32,0, 32,0) GATE(0,8, 2,0, 2,0)
    GATE(0,9, 1,0, 1,0)
    // layer 1 (A = K)
    GATE(1,0, 24,0, 16,0)  GATE(1,1, 12,0, 24,0) GATE(1,2, 4,8, 28,0)
    GATE(1,3, 0,12, 28,8)  GATE(1,4, 0,6, 28,12) GATE(1,5, 0,3, 28,14)
    GATE(1,6, 32,1, 28,15) GATE(1,7, 34,0, 60,15) GATE(1,8, 3,0, 62,15)
    GATE(1,9, 1,0, 63,15)
    // layer 2 (A = K^2)
    GATE(2,0, 20,0, 16,0)  GATE(2,1, 8,8, 8,0)   GATE(2,2, 4,4, 20,0)
    GATE(2,3, 0,10, 8,8)   GATE(2,4, 0,5, 20,4)  GATE(2,5, 32,2, 8,10)
    GATE(2,6, 2,1, 20,5)   GATE(2,7, 33,0, 40,10) GATE(2,8, 2,0, 22,5)
    GATE(2,9, 1,0, 41,10)
    // layer 3 (A = K^3)
    GATE(3,0, 28,8, 16,0)  GATE(3,1, 12,12, 24,0) GATE(3,2, 4,14, 12,0)
    GATE(3,3, 0,15, 4,8)   GATE(3,4, 32,7, 16,12) GATE(3,5, 34,3, 24,6)
    GATE(3,6, 35,1, 12,3)  GATE(3,7, 35,0, 36,9)  GATE(3,8, 3,0, 50,12)
    GATE(3,9, 1,0, 27,6)
#undef GATE

    // epilogue: probabilities, reg-space signed folds, 5 lane-space WHTs
    float p[16];
    #pragma unroll
    for (int r = 0; r < 16; ++r) p[r] = re[r] * re[r] + im[r] * im[r];
    float a[8], f8 = 0.0f;
    #pragma unroll
    for (int r = 0; r < 8; ++r) { a[r] = p[r] + p[r + 8]; f8 += p[r] - p[r + 8]; }
    float c4[4], f4 = 0.0f;
    #pragma unroll
    for (int r = 0; r < 4; ++r) { c4[r] = a[r] + a[r + 4]; f4 += a[r] - a[r + 4]; }
    float e2[2], f2 = 0.0f;
    #pragma unroll
    for (int r = 0; r < 2; ++r) { e2[r] = c4[r] + c4[r + 2]; f2 += c4[r] - c4[r + 2]; }
    float P  = e2[0] + e2[1];
    float f1 = e2[0] - e2[1];

    float wP = wht6(P,  lane, selP);
    float w8 = wht6(f8, lane, selP);
    float w4 = wht6(f4, lane, selP);
    float w2 = wht6(f2, lane, selP);
    float w1 = wht6(f1, lane, selP);

    // rows of K^4: {i, i-4, i-8} -> (value, lane index)
    float* o = out + b * NQ;
    if (lane == 16) { o[0] = wP; o[4] = w4; }
    if (lane ==  8) { o[1] = wP; o[5] = w2; }
    if (lane ==  4) { o[2] = wP; o[6] = w1; }
    if (lane ==  0) { o[3] = w8; }
    if (lane == 32) { o[7] = w8; }
    if (lane == 18) { o[8] = w4; }
    if (lane ==  9) { o[9] = w2; }
}

extern "C" void kernel_launch(void* const* d_in, const int* in_sizes, int n_in,
                              void* d_out, int out_size, void* d_ws, size_t ws_size,
                              hipStream_t stream) {
    const float* x  = (const float*)d_in[0];
    const float* qp = (const float*)d_in[1];
    float* out = (float*)d_out;
    const int B = in_sizes[0] / NQ;
    const int blocks = (B + WPB - 1) / WPB;
    qlayer_kernel<<<blocks, NTHREADS, 0, stream>>>(x, qp, out, B);
}

// Round 6
// 75.428 us; speedup vs baseline: 1.5376x; 1.0643x over previous
//
#include <hip/hip_runtime.h>
#include <math.h>

#define NQ 10
#define NL 4
#define NGATES (NL * NQ)
#define NTHREADS 256
#define WPB 4   // waves per block

typedef float f32x2 __attribute__((ext_vector_type(2)));

#if __has_builtin(__builtin_amdgcn_permlane32_swap)
#define HAVE_PLSWAP 1
#else
#define HAVE_PLSWAP 0
#endif

// ---------------------------------------------------------------------------
// Physical bit layout (10-bit state index split lane(6)/reg(4)):
//   qubit0 -> lane 16   qubit1 -> lane 8   qubit2 -> lane 4   (ds_swizzle bits)
//   qubit7 -> lane 32 (permlane)  qubit8 -> lane 2 (DPP)  qubit9 -> lane 1 (DPP)
//   qubit3 -> reg 8   qubit4 -> reg 4   qubit5 -> reg 2   qubit6 -> reg 1
// CNOT chain K = prefix-parity matrix; CNOTs absorbed into basis relabeling.
// Gate on qubit q in layer l: xor-mask m = K^{-l} e_q, select s = row_q(K^l).
// All 40 (mask, select) pairs constexpr (validated rounds 2-5).
// ---------------------------------------------------------------------------

// 32-bit xor-exchange by compile-time lane mask XM
template<int XM>
__device__ __forceinline__ float exch1(float v, bool selP) {
    if constexpr (XM == 0) return v;
    int x = __float_as_int(v);
    constexpr int low = XM & 31;
    if constexpr (low == 1)      x = __builtin_amdgcn_mov_dpp(x, 0xB1, 0xF, 0xF, true);
    else if constexpr (low == 2) x = __builtin_amdgcn_mov_dpp(x, 0x4E, 0xF, 0xF, true);
    else if constexpr (low == 3) x = __builtin_amdgcn_mov_dpp(x, 0x1B, 0xF, 0xF, true);
    else if constexpr (low != 0) x = __builtin_amdgcn_ds_swizzle(x, (low << 10) | 0x1F);
    if constexpr ((XM & 32) != 0) {
#if HAVE_PLSWAP
        auto r = __builtin_amdgcn_permlane32_swap((unsigned)x, (unsigned)x, false, false);
        x = selP ? (int)r[0] : (int)r[1];
#else
        x = __float_as_int(__shfl_xor(__int_as_float(x), 32, 64));
#endif
    }
    return __int_as_float(x);
}

template<int XM>
__device__ __forceinline__ f32x2 exch2(f32x2 v, bool selP) {
    f32x2 r;
    r.x = exch1<XM>(v.x, selP);
    r.y = exch1<XM>(v.y, selP);
    return r;
}

// complex t = A*st + B*pst, all (re,im) VGPR pairs; 4 VOP3P packed-f32 ops.
//  t.lo = A.lo*st.lo - A.hi*st.hi + B.lo*pst.lo - B.hi*pst.hi
//  t.hi = A.lo*st.hi + A.hi*st.lo + B.lo*pst.hi + B.hi*pst.lo
__device__ __forceinline__ f32x2 cfma4(f32x2 A, f32x2 st, f32x2 B, f32x2 pst) {
    f32x2 t;
    asm("v_pk_mul_f32 %0, %1, %2 op_sel:[0,0] op_sel_hi:[0,1]\n\t"
        "v_pk_fma_f32 %0, %1, %2, %0 op_sel:[1,1,0] op_sel_hi:[1,0,1] neg_lo:[0,1,0]\n\t"
        "v_pk_fma_f32 %0, %3, %4, %0 op_sel:[0,0,0] op_sel_hi:[0,1,1]\n\t"
        "v_pk_fma_f32 %0, %3, %4, %0 op_sel:[1,1,0] op_sel_hi:[1,0,1] neg_lo:[0,1,0]"
        : "=&v"(t)
        : "v"(A), "v"(st), "v"(B), "v"(pst));
    return t;
}

// generalized 1q gate: pair (p, p^m); select h = parity(p & s)
template<int XM, int XR, int SL, int SR>
__device__ __forceinline__ void gate(f32x2 (&st)[16], const f32x2* g4,
                                     int lane, bool selP) {
    f32x2 u00 = g4[0], u01 = g4[1], u10 = g4[2], u11 = g4[3];
    bool hl = (__popc(lane & SL) & 1) != 0;
    f32x2 A0, B0, A1, B1;
    A0.x = hl ? u11.x : u00.x;  A0.y = hl ? u11.y : u00.y;
    B0.x = hl ? u10.x : u01.x;  B0.y = hl ? u10.y : u01.y;
    A1.x = hl ? u00.x : u11.x;  A1.y = hl ? u00.y : u11.y;
    B1.x = hl ? u01.x : u10.x;  B1.y = hl ? u01.y : u10.y;
    f32x2 pst[16];
    #pragma unroll
    for (int r = 0; r < 16; ++r) pst[r] = exch2<XM>(st[r ^ XR], selP);
    #pragma unroll
    for (int r = 0; r < 16; ++r) {
        const bool p1 = (__builtin_popcount(r & SR) & 1) != 0;  // folds post-unroll
        f32x2 Ar = p1 ? A1 : A0;
        f32x2 Br = p1 ? B1 : B0;
        st[r] = cfma4(Ar, st[r], Br, pst[r]);
    }
}

// 6-stage signed butterfly: lane L ends with sum_j (-1)^{popcount(L&j)} v_j
__device__ __forceinline__ float wht6(float v, int lane, bool selP) {
    float t;
    t = exch1<1>(v, selP);   v = (lane & 1)  ? (t - v) : (v + t);
    t = exch1<2>(v, selP);   v = (lane & 2)  ? (t - v) : (v + t);
    t = exch1<4>(v, selP);   v = (lane & 4)  ? (t - v) : (v + t);
    t = exch1<8>(v, selP);   v = (lane & 8)  ? (t - v) : (v + t);
    t = exch1<16>(v, selP);  v = (lane & 16) ? (t - v) : (v + t);
    t = exch1<32>(v, selP);  v = (lane & 32) ? (t - v) : (v + t);
    return v;
}

__global__ __launch_bounds__(NTHREADS, 2) void qlayer_kernel(
    const float* __restrict__ x,
    const float* __restrict__ qp,
    float* __restrict__ out,
    int B)
{
    __shared__ f32x2 su[NGATES][4];   // {u00, u01, u10, u11} as (re,im) pairs

    const int t = threadIdx.x;
    // --- build gate matrices U = Rz @ Ry @ Rx, threads 0..39 ---
    if (t < NGATES) {
        float w0 = qp[t * 3 + 0], w1 = qp[t * 3 + 1], w2 = qp[t * 3 + 2];
        float cx = __cosf(0.5f * w0), sx = __sinf(0.5f * w0);
        float cy = __cosf(0.5f * w1), sy = __sinf(0.5f * w1);
        float er = __cosf(0.5f * w2), ei = -__sinf(0.5f * w2);   // ez = exp(-i w2/2)
        float m00r =  cy * cx, m00i =  sy * sx;
        float m01r = -sy * cx, m01i = -cy * sx;
        float m10r =  sy * cx, m10i = -cy * sx;
        float m11r =  cy * cx, m11i = -sy * sx;
        f32x2 v;
        v.x = er * m00r - ei * m00i;  v.y = er * m00i + ei * m00r;  su[t][0] = v;
        v.x = er * m01r - ei * m01i;  v.y = er * m01i + ei * m01r;  su[t][1] = v;
        v.x = er * m10r + ei * m10i;  v.y = er * m10i - ei * m10r;  su[t][2] = v;
        v.x = er * m11r + ei * m11i;  v.y = er * m11i - ei * m11r;  su[t][3] = v;
    }
    __syncthreads();

    const int lane = t & 63;
    const int b = blockIdx.x * WPB + (t >> 6);
    if (b >= B) return;

    // runtime probe: which permlane32_swap output holds the lane^32 partner
    bool selP = false;
#if HAVE_PLSWAP
    {
        auto pr = __builtin_amdgcn_permlane32_swap((unsigned)lane, (unsigned)lane, false, false);
        selP = ((int)pr[0] == (lane ^ 32));
    }
#endif

    float c[NQ], s[NQ];
    #pragma unroll
    for (int q = 0; q < NQ; ++q) {
        float h = 0.5f * x[b * NQ + q];
        c[q] = __cosf(h);  s[q] = __sinf(h);
    }

    // initial product state per physical layout
    float lf = ((lane & 16) ? s[0] : c[0]) * ((lane & 8) ? s[1] : c[1]) *
               ((lane &  4) ? s[2] : c[2]) * ((lane & 32) ? s[7] : c[7]) *
               ((lane &  2) ? s[8] : c[8]) * ((lane &  1) ? s[9] : c[9]);
    f32x2 st[16];
    #pragma unroll
    for (int r = 0; r < 16; ++r) {
        st[r].x = lf * ((r & 8) ? s[3] : c[3]) * ((r & 4) ? s[4] : c[4]) *
                       ((r & 2) ? s[5] : c[5]) * ((r & 1) ? s[6] : c[6]);
        st[r].y = 0.0f;
    }

#define GATE(L, Q, XM, XR, SLm, SRm) \
    gate<XM, XR, SLm, SRm>(st, &su[(L)*NQ+(Q)][0], lane, selP);

    // layer 0 (A = I)
    GATE(0,0, 16,0, 16,0)  GATE(0,1, 8,0, 8,0)   GATE(0,2, 4,0, 4,0)
    GATE(0,3, 0,8, 0,8)    GATE(0,4, 0,4, 0,4)   GATE(0,5, 0,2, 0,2)
    GATE(0,6, 0,1, 0,1)    GATE(0,7, 32,0, 32,0) GATE(0,8, 2,0, 2,0)
    GATE(0,9, 1,0, 1,0)
    // layer 1 (A = K)
    GATE(1,0, 24,0, 16,0)  GATE(1,1, 12,0, 24,0) GATE(1,2, 4,8, 28,0)
    GATE(1,3, 0,12, 28,8)  GATE(1,4, 0,6, 28,12) GATE(1,5, 0,3, 28,14)
    GATE(1,6, 32,1, 28,15) GATE(1,7, 34,0, 60,15) GATE(1,8, 3,0, 62,15)
    GATE(1,9, 1,0, 63,15)
    // layer 2 (A = K^2)
    GATE(2,0, 20,0, 16,0)  GATE(2,1, 8,8, 8,0)   GATE(2,2, 4,4, 20,0)
    GATE(2,3, 0,10, 8,8)   GATE(2,4, 0,5, 20,4)  GATE(2,5, 32,2, 8,10)
    GATE(2,6, 2,1, 20,5)   GATE(2,7, 33,0, 40,10) GATE(2,8, 2,0, 22,5)
    GATE(2,9, 1,0, 41,10)
    // layer 3 (A = K^3)
    GATE(3,0, 28,8, 16,0)  GATE(3,1, 12,12, 24,0) GATE(3,2, 4,14, 12,0)
    GATE(3,3, 0,15, 4,8)   GATE(3,4, 32,7, 16,12) GATE(3,5, 34,3, 24,6)
    GATE(3,6, 35,1, 12,3)  GATE(3,7, 35,0, 36,9)  GATE(3,8, 3,0, 50,12)
    GATE(3,9, 1,0, 27,6)
#undef GATE

    // epilogue: probabilities, reg-space signed folds, 5 lane-space WHTs
    float p[16];
    #pragma unroll
    for (int r = 0; r < 16; ++r) p[r] = st[r].x * st[r].x + st[r].y * st[r].y;
    float a[8], f8 = 0.0f;
    #pragma unroll
    for (int r = 0; r < 8; ++r) { a[r] = p[r] + p[r + 8]; f8 += p[r] - p[r + 8]; }
    float c4[4], f4 = 0.0f;
    #pragma unroll
    for (int r = 0; r < 4; ++r) { c4[r] = a[r] + a[r + 4]; f4 += a[r] - a[r + 4]; }
    float e2[2], f2 = 0.0f;
    #pragma unroll
    for (int r = 0; r < 2; ++r) { e2[r] = c4[r] + c4[r + 2]; f2 += c4[r] - c4[r + 2]; }
    float P  = e2[0] + e2[1];
    float f1 = e2[0] - e2[1];

    float wP = wht6(P,  lane, selP);
    float w8 = wht6(f8, lane, selP);
    float w4 = wht6(f4, lane, selP);
    float w2 = wht6(f2, lane, selP);
    float w1 = wht6(f1, lane, selP);

    // rows of K^4: {i, i-4, i-8} -> (value, lane index)
    float* o = out + b * NQ;
    if (lane == 16) { o[0] = wP; o[4] = w4; }
    if (lane ==  8) { o[1] = wP; o[5] = w2; }
    if (lane ==  4) { o[2] = wP; o[6] = w1; }
    if (lane ==  0) { o[3] = w8; }
    if (lane == 32) { o[7] = w8; }
    if (lane == 18) { o[8] = w4; }
    if (lane ==  9) { o[9] = w2; }
}

extern "C" void kernel_launch(void* const* d_in, const int* in_sizes, int n_in,
                              void* d_out, int out_size, void* d_ws, size_t ws_size,
                              hipStream_t stream) {
    const float* x  = (const float*)d_in[0];
    const float* qp = (const float*)d_in[1];
    float* out = (float*)d_out;
    const int B = in_sizes[0] / NQ;
    const int blocks = (B + WPB - 1) / WPB;
    qlayer_kernel<<<blocks, NTHREADS, 0, stream>>>(x, qp, out, B);
}